// Round 8
// baseline (2835.841 us; speedup 1.0000x reference)
//
#include <hip/hip_runtime.h>
#include <hip/hip_fp16.h>

#define B_ 256
#define T_ 1200
#define I_ 16
#define H_ 128

typedef __attribute__((ext_vector_type(2))) _Float16 h2;
typedef __attribute__((ext_vector_type(8))) _Float16 f16x8;

union f16x8u { f16x8 v; h2 h[4]; _Float16 s[8]; };

#if __has_builtin(__builtin_amdgcn_fdot2)
__device__ __forceinline__ float fdot2(h2 a, h2 b, float c) {
  return __builtin_amdgcn_fdot2(a, b, c, false);  // v_dot2_f32_f16
}
#else
__device__ __forceinline__ float fdot2(h2 a, h2 b, float c) {
  return fmaf((float)a.x, (float)b.x, fmaf((float)a.y, (float)b.y, c));
}
#endif

template <int CTRL>
__device__ __forceinline__ float dppadd(float x) {
  return x + __int_as_float(__builtin_amdgcn_update_dpp(0, __float_as_int(x), CTRL, 0xF, 0xF, true));
}

// 8-lane (oct) k-reduction: xor1, xor2, then row_half_mirror (== xor4 once
// quad-uniform). All on the VALU DPP path. Validated in rounds 2/6.
__device__ __forceinline__ float qsum8(float x) {
  x = dppadd<0xB1>(x);    // quad_perm xor1
  x = dppadd<0x4E>(x);    // quad_perm xor2
  x = dppadd<0x141>(x);   // row_half_mirror ~ xor4
  return x;
}

// sum oct-uniform values across the 8 octs of a wave
__device__ __forceinline__ float ored(float x) {
  x = dppadd<0x140>(x);   // row_mirror ~ xor8 (oct-uniform input)
  x += __shfl_xor(x, 16);
  x += __shfl_xor(x, 32);
  return x;
}

__device__ __forceinline__ float sigm(float x) {
  return __builtin_amdgcn_rcpf(1.f + __expf(-x));
}
__device__ __forceinline__ float tanh_(float x) {
  return 1.f - 2.f * __builtin_amdgcn_rcpf(1.f + __expf(2.f * x));
}

// lgkm-only barrier: global stores (out[]) stay in flight across regions.
// The "memory" clobber also forces per-region re-read of LDS-resident biases
// (keeps them out of the register budget).
__device__ __forceinline__ void lds_barrier() {
  __builtin_amdgcn_sched_barrier(0);
  asm volatile("s_waitcnt lgkmcnt(0)" ::: "memory");
  __builtin_amdgcn_s_barrier();
  __builtin_amdgcn_sched_barrier(0);
}

// ---------------------------------------------------------------------------
// Fully fused 2-layer LSTM + head. ONE kernel, 1 block (1024 thr) per batch
// row. Oct layout: 8 lanes (c=tid&7) share cell j=tid>>3; lane c holds the
// k-slice [16c,16c+16) of ALL FOUR gate rows of Whh0, Wih1, Whh1
// (3*4*8 = 96 h2) + Wih0 slice (4 h2). 1024 thr = 4 waves/SIMD -> 128-reg
// unified capacity/thread; demand ~122 -> no scratch (AGPR half holds
// weights, v_dot2 reads them directly; round-6 evidence).
// Layer 1 skewed one region behind layer 0 (region u: L0 makes h0_u, L1
// makes h1_{u-1}; both read h0b[rb]=h0_{u-1}). After qsum8 every lane owns
// all 4 gate pre-acts of its j -> cell computed in-lane (no broadcast).
// One lgkm-only barrier per region; deferred head + rotating collector.
// 1203 serial regions. ZERO workspace.
// ---------------------------------------------------------------------------
__global__ __launch_bounds__(1024, 4) void lstm_oct(
    const float* __restrict__ xin,
    const float* __restrict__ Wih0, const float* __restrict__ Whh0,
    const float* __restrict__ bih0, const float* __restrict__ bhh0,
    const float* __restrict__ Wih1, const float* __restrict__ Whh1,
    const float* __restrict__ bih1, const float* __restrict__ bhh1,
    const float* __restrict__ Wlin, const float* __restrict__ blin,
    float* __restrict__ out)
{
  __shared__ __align__(16) __half xs[T_ * I_];   // 38400 B, staged once
  __shared__ __align__(16) __half h0b[2][H_];
  __shared__ __align__(16) __half h1b[2][H_];
  __shared__ __align__(16) float lbs[H_][8];     // [j][gate 0-3 L0, 4-7 L1]
  __shared__ __align__(16) float red[2][16];     // per-wave head partials

  const int tid = threadIdx.x;
  const int c = tid & 7;          // k-slice [16c, 16c+16)
  const int j = tid >> 3;         // cell index, 0..127
  const int b = blockIdx.x;

  // ---- stage x[b] -> LDS fp16 (coalesced float4 reads) ----
  {
    const float4* xg4 = (const float4*)(xin + (size_t)b * T_ * I_);
    for (int idx = tid; idx < T_ * I_ / 4; idx += 1024) {
      const float4 v = xg4[idx];
      xs[4 * idx]     = __float2half(v.x);
      xs[4 * idx + 1] = __float2half(v.y);
      xs[4 * idx + 2] = __float2half(v.z);
      xs[4 * idx + 3] = __float2half(v.w);
    }
  }

  // ---- weights: 96 h2 + 4 h2 per thread ----
  h2 wA[4][8], wI[4][8], wH[4][8], wx[4];
#pragma unroll
  for (int q = 0; q < 4; ++q) {
    const int g = q * H_ + j;
    const float* pA = Whh0 + (size_t)g * H_ + c * 16;
    const float* pI = Wih1 + (size_t)g * H_ + c * 16;
    const float* pH = Whh1 + (size_t)g * H_ + c * 16;
#pragma unroll
    for (int i = 0; i < 4; ++i) {
      float4 v = *(const float4*)(pA + 4 * i);
      wA[q][2*i].x   = (_Float16)v.x; wA[q][2*i].y   = (_Float16)v.y;
      wA[q][2*i+1].x = (_Float16)v.z; wA[q][2*i+1].y = (_Float16)v.w;
      v = *(const float4*)(pI + 4 * i);
      wI[q][2*i].x   = (_Float16)v.x; wI[q][2*i].y   = (_Float16)v.y;
      wI[q][2*i+1].x = (_Float16)v.z; wI[q][2*i+1].y = (_Float16)v.w;
      v = *(const float4*)(pH + 4 * i);
      wH[q][2*i].x   = (_Float16)v.x; wH[q][2*i].y   = (_Float16)v.y;
      wH[q][2*i+1].x = (_Float16)v.z; wH[q][2*i+1].y = (_Float16)v.w;
    }
    const float2 vx = *(const float2*)(Wih0 + (size_t)g * I_ + 2 * c);
    wx[q].x = (_Float16)vx.x; wx[q].y = (_Float16)vx.y;
  }

  if (tid < H_) {
#pragma unroll
    for (int q = 0; q < 4; ++q) {
      lbs[tid][q]     = bih0[q * H_ + tid] + bhh0[q * H_ + tid];
      lbs[tid][4 + q] = bih1[q * H_ + tid] + bhh1[q * H_ + tid];
    }
    h0b[0][tid] = __float2half(0.f);
    h1b[0][tid] = __float2half(0.f);
    h1b[1][tid] = __float2half(0.f);
  }
  const float wl = Wlin[j];   // oct-uniform; ored sums distinct j only
  const float bl = blin[0];

  float cst0 = 0.f, cst1 = 0.f, hv1p = 0.f;
  float* op = out + (size_t)b * T_;
  __syncthreads();   // drains staging loads once

#pragma unroll 1
  for (int u = 0; u <= T_ + 2; ++u) {
    const int rb = u & 1, nb = rb ^ 1;

    // ---- deferred head for h1_{u-2} (register-resident from last region) ----
    if (u >= 2 && u <= T_ + 1) {
      const float val = ored(fmaxf(hv1p, 0.f) * wl);
      if ((tid & 63) == 0) red[rb][tid >> 6] = val;
    }
    // ---- rotating collector: emit out[u-3] (fire-and-forget store) ----
    if (u >= 3) {
      const int m = u - 3;
      if (tid == ((m & 15) << 6)) {
        const float4 r0 = *(const float4*)(&red[nb][0]);
        const float4 r1 = *(const float4*)(&red[nb][4]);
        const float4 r2 = *(const float4*)(&red[nb][8]);
        const float4 r3 = *(const float4*)(&red[nb][12]);
        op[m] = bl
            + r0.x + r0.y + r0.z + r0.w + r1.x + r1.y + r1.z + r1.w
            + r2.x + r2.y + r2.z + r2.w + r3.x + r3.y + r3.z + r3.w;
      }
    }

    // biases re-read per region (barrier clobber prevents hoisting to regs)
    const float4 bs0v = *(const float4*)(&lbs[j][0]);
    const float4 bs1v = *(const float4*)(&lbs[j][4]);

    // ---- L0 dots: Whh0 . h0_{u-1}  +  Wih0 . x_u ----
    const int xi = (u < T_) ? u : 0;
    const h2 xv = *(const h2*)(&xs[xi * I_ + 2 * c]);
    float A0 = 0.f, A1 = 0.f, A2 = 0.f, A3 = 0.f;
    {
      f16x8u ua, ub;
      ua.v = *(const f16x8*)(&h0b[rb][c * 16]);
      ub.v = *(const f16x8*)(&h0b[rb][c * 16 + 8]);
#pragma unroll
      for (int k = 0; k < 4; ++k) {
        A0 = fdot2(wA[0][k], ua.h[k], A0);
        A1 = fdot2(wA[1][k], ua.h[k], A1);
        A2 = fdot2(wA[2][k], ua.h[k], A2);
        A3 = fdot2(wA[3][k], ua.h[k], A3);
      }
#pragma unroll
      for (int k = 0; k < 4; ++k) {
        A0 = fdot2(wA[0][4 + k], ub.h[k], A0);
        A1 = fdot2(wA[1][4 + k], ub.h[k], A1);
        A2 = fdot2(wA[2][4 + k], ub.h[k], A2);
        A3 = fdot2(wA[3][4 + k], ub.h[k], A3);
      }
    }
    A0 = fdot2(wx[0], xv, A0);
    A1 = fdot2(wx[1], xv, A1);
    A2 = fdot2(wx[2], xv, A2);
    A3 = fdot2(wx[3], xv, A3);
    if (u < T_) {   // ---- L0 cell for step u ----
      const float g0 = qsum8(A0) + bs0v.x;
      const float g1 = qsum8(A1) + bs0v.y;
      const float g2 = qsum8(A2) + bs0v.z;
      const float g3 = qsum8(A3) + bs0v.w;
      const float ig = sigm(g0), fg = sigm(g1), gg = tanh_(g2), og = sigm(g3);
      cst0 = fg * cst0 + ig * gg;
      const float hv0 = og * tanh_(cst0);
      if (c == 0) h0b[nb][j] = __float2half(hv0);
    }

    // ---- L1 dots: Wih1 . h0_{u-1}  +  Whh1 . h1_{u-2} ----
    float C0 = 0.f, C1 = 0.f, C2 = 0.f, C3 = 0.f;
    {
      f16x8u ua, ub, va, vb;
      ua.v = *(const f16x8*)(&h0b[rb][c * 16]);
      ub.v = *(const f16x8*)(&h0b[rb][c * 16 + 8]);
      va.v = *(const f16x8*)(&h1b[rb][c * 16]);
      vb.v = *(const f16x8*)(&h1b[rb][c * 16 + 8]);
#pragma unroll
      for (int k = 0; k < 4; ++k) {
        C0 = fdot2(wI[0][k], ua.h[k], C0);
        C1 = fdot2(wI[1][k], ua.h[k], C1);
        C2 = fdot2(wI[2][k], ua.h[k], C2);
        C3 = fdot2(wI[3][k], ua.h[k], C3);
      }
#pragma unroll
      for (int k = 0; k < 4; ++k) {
        C0 = fdot2(wI[0][4 + k], ub.h[k], C0);
        C1 = fdot2(wI[1][4 + k], ub.h[k], C1);
        C2 = fdot2(wI[2][4 + k], ub.h[k], C2);
        C3 = fdot2(wI[3][4 + k], ub.h[k], C3);
      }
#pragma unroll
      for (int k = 0; k < 4; ++k) {
        C0 = fdot2(wH[0][k], va.h[k], C0);
        C1 = fdot2(wH[1][k], va.h[k], C1);
        C2 = fdot2(wH[2][k], va.h[k], C2);
        C3 = fdot2(wH[3][k], va.h[k], C3);
      }
#pragma unroll
      for (int k = 0; k < 4; ++k) {
        C0 = fdot2(wH[0][4 + k], vb.h[k], C0);
        C1 = fdot2(wH[1][4 + k], vb.h[k], C1);
        C2 = fdot2(wH[2][4 + k], vb.h[k], C2);
        C3 = fdot2(wH[3][4 + k], vb.h[k], C3);
      }
    }
    if (u >= 1 && u <= T_) {   // ---- L1 cell for step u-1 ----
      const float g0 = qsum8(C0) + bs1v.x;
      const float g1 = qsum8(C1) + bs1v.y;
      const float g2 = qsum8(C2) + bs1v.z;
      const float g3 = qsum8(C3) + bs1v.w;
      const float ig = sigm(g0), fg = sigm(g1), gg = tanh_(g2), og = sigm(g3);
      cst1 = fg * cst1 + ig * gg;
      hv1p = og * tanh_(cst1);
      if (c == 0) h1b[nb][j] = __float2half(hv1p);
    }

    lds_barrier();
  }
}

extern "C" void kernel_launch(void* const* d_in, const int* in_sizes, int n_in,
                              void* d_out, int out_size, void* d_ws, size_t ws_size,
                              hipStream_t stream) {
  // Single fused kernel; zero workspace (d_ws unused).
  lstm_oct<<<B_, 1024, 0, stream>>>(
      (const float*)d_in[0],
      (const float*)d_in[1], (const float*)d_in[2],
      (const float*)d_in[3], (const float*)d_in[4],
      (const float*)d_in[5], (const float*)d_in[6],
      (const float*)d_in[7], (const float*)d_in[8],
      (const float*)d_in[9], (const float*)d_in[10],
      (float*)d_out);
}